// Round 5
// baseline (131.897 us; speedup 1.0000x reference)
//
#include <hip/hip_runtime.h>
#include <stdint.h>

// TimeVaryingDelayLine forward — LDS multi-pass gather, v3 (double-buffered).
//
// R4 was structurally serialized: single LDS buffer -> stage, drain, compute
// per pass with nothing overlapped (VALUBusy 17.7%, ~75% stall). v3 splits
// LDS into two 32KB buffers and issues the NEXT pass's global_load_lds
// BEFORE computing the current pass; the __syncthreads() at pass end then
// only pays the latency remainder (T3 "minimum 2-phase" pattern).
//
// Block = 256 threads x 32 elems = 8192 contiguous t of one series.
// Window = xpad[t0, t0+49152) staged in 6 passes x 8192 floats (32KB).
// S_BYTES = 2^15 -> per-element pass test = add + unsigned cmp.

#define MAX_DELAY 40000
#define T_LEN     1000000
#define XPAD      (MAX_DELAY + T_LEN)   // 1,040,000 floats per series
#define CHUNK     8192
#define S_ELEMS   8192
#define S_BYTES   (S_ELEMS * 4)         // 32768 = 2^15
#define NPASS     6                     // 6*8192 = 49152 >= 40000+8192
#define CPS       123                   // ceil(T_LEN/CHUNK)
#define NXCD      8

typedef __attribute__((address_space(3))) uint32_t       lds_u32;
typedef const __attribute__((address_space(1))) uint32_t glb_u32;

__global__ __launch_bounds__(256, 2) void tvdl_kernel(
    const float* __restrict__ x,
    const float* __restrict__ dt,
    const float* __restrict__ buf,
    float* __restrict__ y,
    int chunk_per_xcd)
{
    __shared__ float lds[2][S_ELEMS];

    int bid = blockIdx.x;
    int lb  = (bid & (NXCD - 1)) * chunk_per_xcd + (bid >> 3);  // XCD-contiguous
    int nc  = lb / CPS;                 // series 0..15
    int c   = lb - nc * CPS;            // chunk 0..122
    int t0  = c * CHUNK;
    int tid = threadIdx.x;

    const float* __restrict__ xs  = x   + (size_t)nc * T_LEN;
    const float* __restrict__ bs  = buf + (size_t)nc * MAX_DELAY;
    const float* __restrict__ dts = dt  + (size_t)nc * T_LEN;
    float*       __restrict__ ys  = y   + (size_t)nc * T_LEN;

    // ---- per-element setup: read dt once, keep (b1, frac, acc) in regs ----
    int   b1[8][4];     // byte offset of tap1 relative to window start
    float fr[8][4];
    float acc[8][4];

#pragma unroll
    for (int k = 0; k < 8; ++k) {
        int go   = (k * 256 + tid) * 4;
        int lidx = t0 + go;
        int lc   = lidx > T_LEN - 4 ? T_LEN - 4 : lidx;   // tail-chunk clamp
        float4 d4 = *reinterpret_cast<const float4*>(dts + lc);
        float dv[4] = {d4.x, d4.y, d4.z, d4.w};
#pragma unroll
        for (int j = 0; j < 4; ++j) {
            float dvj = dv[j];
            int   i0  = (int)dvj;                 // dt >= 0 -> trunc == floor
            fr[k][j]  = dvj - (float)i0;
            b1[k][j]  = (MAX_DELAY - 1 + (go + j) - i0) * 4;
            acc[k][j] = 0.0f;
        }
    }

    // ---- staging macro: pass p -> lds[b] via direct-to-LDS DMA ----
    // 8 x (64 lanes x 16B) per wave = 8KB/wave, 32KB/block.
#define STAGE(b, p)                                                          \
    {                                                                        \
        _Pragma("unroll")                                                    \
        for (int q = 0; q < 8; ++q) {                                        \
            int g = t0 + (p) * S_ELEMS + (q * 256 + tid) * 4;                \
            if (g > XPAD - 4) g = XPAD - 4;                                  \
            const float* src = (g >= MAX_DELAY) ? (xs + (g - MAX_DELAY))     \
                                                : (bs + g);                  \
            float* dst = lds[b] + (size_t)(q * 256 + (tid & 192)) * 4;       \
            __builtin_amdgcn_global_load_lds((glb_u32*)src, (lds_u32*)dst,   \
                                             16, 0, 0);                      \
        }                                                                    \
    }

    // prologue
    STAGE(0, 0);
    __syncthreads();                    // drains vmcnt -> lds[0] ready

    // ---- pass loop: stage next (async) || compute current ----
#pragma unroll
    for (int p = 0; p < NPASS; ++p) {
        const int cur = p & 1;
        if (p + 1 < NPASS) STAGE(cur ^ 1, p + 1);

        const float* lb0 = lds[cur];
#pragma unroll
        for (int k = 0; k < 8; ++k) {
#pragma unroll
            for (int j = 0; j < 4; ++j) {
                int      bb = b1[k][j] - p * S_BYTES;     // const per pass
                unsigned ub = (unsigned)bb;
                if (ub < (unsigned)(S_BYTES - 4)) {
                    // both taps resident: tap1 at ub, tap0 at ub+4
                    const float* lp = (const float*)((const char*)lb0 + ub);
                    float t1v = lp[0];
                    float t0v = lp[1];
                    float f   = fr[k][j];
                    acc[k][j] = fmaf(1.0f - f, t0v, fmaf(f, t1v, acc[k][j]));
                } else if (ub == (unsigned)(S_BYTES - 4)) {
                    // tap1 is last slot of this pass; tap0 arrives next pass
                    acc[k][j] = fmaf(fr[k][j], lb0[S_ELEMS - 1], acc[k][j]);
                } else if (bb == -4) {
                    // tap0 is slot 0 here; tap1 was last slot of prev pass
                    acc[k][j] = fmaf(1.0f - fr[k][j], lb0[0], acc[k][j]);
                }
            }
        }

        // one barrier per pass: all waves done reading lds[cur] AND this
        // wave's stage loads (the only outstanding vmem) have landed.
        if (p + 1 < NPASS) __syncthreads();
    }
#undef STAGE

    // ---- store ----
#pragma unroll
    for (int k = 0; k < 8; ++k) {
        int go = (k * 256 + tid) * 4;
        if (t0 + go < T_LEN) {
            *reinterpret_cast<float4*>(ys + t0 + go) =
                make_float4(acc[k][0], acc[k][1], acc[k][2], acc[k][3]);
        }
    }
}

extern "C" void kernel_launch(void* const* d_in, const int* in_sizes, int n_in,
                              void* d_out, int out_size, void* d_ws, size_t ws_size,
                              hipStream_t stream) {
    const float* x   = (const float*)d_in[0];
    const float* dt  = (const float*)d_in[1];
    const float* buf = (const float*)d_in[2];
    float* y = (float*)d_out;

    int nseries = out_size / T_LEN;                 // 16
    int blocks  = nseries * CPS;                    // 1968 = 8 * 246
    int chunk_per_xcd = blocks / NXCD;              // 246
    tvdl_kernel<<<blocks, 256, 0, stream>>>(x, dt, buf, y, chunk_per_xcd);
}